// Round 4
// baseline (562.793 us; speedup 1.0000x reference)
//
#include <hip/hip_runtime.h>
#include <cstdint>
#include <cstddef>

typedef __attribute__((ext_vector_type(8))) short short8;
typedef __attribute__((ext_vector_type(4))) float f32x4;

#define DEV __device__ __forceinline__

DEV unsigned short f2bf(float f) {
  unsigned int u = __float_as_uint(f);
  u += 0x7fffu + ((u >> 16) & 1u);   // round-to-nearest-even
  return (unsigned short)(u >> 16);
}

DEV unsigned int pk2(float a, float b) {
  return (unsigned int)f2bf(a) | ((unsigned int)f2bf(b) << 16);
}

constexpr int NROW = 12288;

// ---------------- P0: t0T = (x @ W0)^T  -> bf16 [128][12288] ----------------
__global__ __launch_bounds__(256) void xw_kernel(
    const float* __restrict__ x, const float* __restrict__ W0,
    unsigned short* __restrict__ t0T) {
  __shared__ float sW[128 * 128];
  __shared__ float sx[16][128];
  const int t = threadIdx.x;
  for (int i = t; i < 128 * 128; i += 256) sW[i] = W0[i];
  const int r0 = blockIdx.x * 16;
  for (int i = t; i < 16 * 128; i += 256)
    sx[i >> 7][i & 127] = x[(size_t)(r0 + (i >> 7)) * 128 + (i & 127)];
  __syncthreads();
  const int c = t & 127;   // output column 0..127
  const int rg = t >> 7;   // row group: rows rg*8 .. rg*8+7
  float acc[8] = {0, 0, 0, 0, 0, 0, 0, 0};
  for (int k = 0; k < 128; ++k) {
    float w = sW[k * 128 + c];
#pragma unroll
    for (int j = 0; j < 8; ++j) acc[j] += sx[rg * 8 + j][k] * w;
  }
  uint4 o;
  o.x = pk2(acc[0], acc[1]);
  o.y = pk2(acc[2], acc[3]);
  o.z = pk2(acc[4], acc[5]);
  o.w = pk2(acc[6], acc[7]);
  *(uint4*)(t0T + (size_t)c * NROW + r0 + rg * 8) = o;
}

// ------------- big GEMM: part[split] = adj_chunk @ t   (bf16 MFMA) -----------
// A: [12288][12288] f32 (adj), BT: [H][12288] bf16 (t transposed)
// part: [KSPLIT][12288][H] f32
// BK=192: each block reads 64 rows x 768B contiguous per step (DRAM-row
// friendly, 3x the old 256B granularity). B fragments are loaded per-kk
// DIRECTLY from L2 into registers (no B LDS): one 16B/lane global load =
// 16 fully-used 64B lines; hot B window (~200KB/step chip-wide) stays
// L2-resident via near-lockstep block progress. A LDS rows padded to 416B
// -> uniform 2-way bank access (free) without XOR swizzle.
// Raw s_barrier + counted vmcnt schedule (R3's win, kept).
template <int H>
__global__ __launch_bounds__(256, 3) void gcn_gemm(
    const float* __restrict__ A, const unsigned short* __restrict__ BT,
    float* __restrict__ part) {
  constexpr int KSPLIT = 4;
  constexpr int BM = 64, BK = 192;
  constexpr int KK = BK / 32;                   // 6 mfma k-chunks per step
  constexpr int WN = (H >= 64) ? 2 : 1;
  constexpr int WM = 4 / WN;
  constexpr int MR = BM / (WM * 16);            // 128/64: 2, 32: 1
  constexpr int NR = H / (WN * 16);             // 128: 4, 64: 2, 32: 2
  constexpr int KSTEPS = (NROW / KSPLIT) / BK;  // 16
  constexpr int LROW = 416;                     // padded A row bytes (2-way banks)
  constexpr int LBUF = BM * LROW;               // 26624 B per buffer

  __shared__ alignas(16) char lds[2 * LBUF];    // 52 KiB -> 3 blocks/CU

  const int t = threadIdx.x;
  const int nmb = NROW / BM;  // 192
  const int bm = blockIdx.x % nmb;
  const int split = blockIdx.x / nmb;
  const int k0 = split * (NROW / KSPLIT);

  // ---- A staging: thread (r=t>>2, q=t&3) owns chunks i=0..5 of row r,
  //      chunk (i,q) = elements i*32 + q*8 .. +8 (32B global read each) ----
  const int r = t >> 2, q = t & 3;
  const float* aptr = A + (size_t)(bm * BM + r) * NROW + k0 + q * 8;
  char* const wbase = lds + r * LROW + q * 16;

  const int wid = t >> 6, lane = t & 63;
  const int l15 = lane & 15, loct = lane >> 4;
  const int wm = wid / WN, wn = wid % WN;

  // ---- B fragment pointers (global, L2-resident stream) ----
  const unsigned short* bp[NR];
#pragma unroll
  for (int n = 0; n < NR; ++n) {
    const int nn = wn * (NR * 16) + n * 16 + l15;
    bp[n] = BT + (size_t)nn * NROW + k0 + loct * 8;
  }

  // ---- A fragment LDS byte offsets ----
  int aoff[MR];
#pragma unroll
  for (int m = 0; m < MR; ++m)
    aoff[m] = (wm * (MR * 16) + m * 16 + l15) * LROW + loct * 16;

  f32x4 acc[MR][NR];
#pragma unroll
  for (int m = 0; m < MR; ++m)
#pragma unroll
    for (int n = 0; n < NR; ++n) acc[m][n] = {0.f, 0.f, 0.f, 0.f};

  float4 av[2 * KK];      // one step's A slice (48 VGPR)
  short8 bfr[2][NR];      // 2-ahead rotating B fragments

  auto issueA = [&](int eoff) {   // eoff in f32 elements from aptr
#pragma unroll
    for (int i = 0; i < KK; ++i) {
      av[2 * i]     = *(const float4*)(aptr + eoff + i * 32);
      av[2 * i + 1] = *(const float4*)(aptr + eoff + i * 32 + 4);
    }
  };
  auto cvtWrite = [&](int buf) {
    char* wb = wbase + buf * LBUF;
#pragma unroll
    for (int i = 0; i < KK; ++i) {
      uint4 w;
      w.x = pk2(av[2 * i].x, av[2 * i].y);
      w.y = pk2(av[2 * i].z, av[2 * i].w);
      w.z = pk2(av[2 * i + 1].x, av[2 * i + 1].y);
      w.w = pk2(av[2 * i + 1].z, av[2 * i + 1].w);
      *(uint4*)(wb + i * 64) = w;
    }
  };

#define LOADB(slot, eoff)                                   \
  {                                                         \
    _Pragma("unroll")                                       \
    for (int n = 0; n < NR; ++n)                            \
      bfr[slot][n] = *(const short8*)(bp[n] + (eoff));      \
  }

#define MFMAK(cb, kk)                                                     \
  {                                                                       \
    short8 af[MR];                                                        \
    _Pragma("unroll")                                                     \
    for (int m = 0; m < MR; ++m)                                          \
      af[m] = *(const short8*)((cb) + aoff[m] + (kk) * 64);               \
    _Pragma("unroll")                                                     \
    for (int m = 0; m < MR; ++m)                                          \
      _Pragma("unroll")                                                   \
      for (int n = 0; n < NR; ++n)                                        \
        acc[m][n] = __builtin_amdgcn_mfma_f32_16x16x32_bf16(              \
            af[m], bfr[(kk) & 1][n], acc[m][n], 0, 0, 0);                 \
  }

  // ---- Prologue: A(0)->lds0; A(1) in flight; B(step0,kk0/1) in flight ----
  issueA(0);
  LOADB(0, 0);
  LOADB(1, 32);
  cvtWrite(0);          // auto-waits A(0) arrival
  issueA(BK);           // A(1), stays in flight across barrier
  asm volatile("s_waitcnt lgkmcnt(0)" ::: "memory");
  __builtin_amdgcn_s_barrier();
  __builtin_amdgcn_sched_barrier(0);

  for (int s = 0; s < KSTEPS; ++s) {
    const char* cb = lds + (s & 1) * LBUF;
    const int nxt = (s & 1) ^ 1;
    MFMAK(cb, 0);
    LOADB(0, 2 * 32);                 // this step kk=2
    MFMAK(cb, 1);
    LOADB(1, 3 * 32);                 // kk=3
    if (s + 1 < KSTEPS) {
      cvtWrite(nxt);                  // auto-waits A(s+1)
      if (s + 2 < KSTEPS) issueA(2 * BK);  // A(s+2) — in flight across barrier
    }
    MFMAK(cb, 2);
    LOADB(0, 4 * 32);                 // kk=4
    MFMAK(cb, 3);
    LOADB(1, 5 * 32);                 // kk=5
    MFMAK(cb, 4);
    if (s + 1 < KSTEPS) LOADB(0, BK);        // next step kk=0
    MFMAK(cb, 5);
    if (s + 1 < KSTEPS) {
      LOADB(1, BK + 32);                     // next step kk=1
#pragma unroll
      for (int n = 0; n < NR; ++n) bp[n] += BK;
      aptr += BK;
      asm volatile("s_waitcnt lgkmcnt(0)" ::: "memory");
      __builtin_amdgcn_s_barrier();          // A(s+2)/B(s+1) stay in flight
      __builtin_amdgcn_sched_barrier(0);
    }
  }

  float* pout = part + ((size_t)split * NROW + (size_t)bm * BM) * H;
#pragma unroll
  for (int m = 0; m < MR; ++m) {
    const int row = wm * (MR * 16) + m * 16 + loct * 4;
#pragma unroll
    for (int n = 0; n < NR; ++n) {
      const int col = wn * (NR * 16) + n * 16 + l15;
#pragma unroll
      for (int rr = 0; rr < 4; ++rr)
        pout[(size_t)(row + rr) * H + col] = acc[m][n][rr];
    }
  }
#undef LOADB
#undef MFMAK
}

// ------- reduce: sum splits + bias + LN + (leaky) + @Wnext -> t_next^T -------
template <int H, int H2, bool ACT>
__global__ __launch_bounds__(256) void reduce_ln(
    const float* __restrict__ part, const float* __restrict__ bias,
    const float* __restrict__ g, const float* __restrict__ be,
    const float* __restrict__ Wn, unsigned short* __restrict__ tT) {
  __shared__ float sW[H * H2];
  __shared__ float sh[4][H];
  const int t = threadIdx.x;
  for (int i = t; i < H * H2; i += 256) sW[i] = Wn[i];
  __syncthreads();

  const int wid = t >> 6, lane = t & 63;
  const int row = blockIdx.x * 4 + wid;
  constexpr int CPL = H / 64;
  float v[CPL];
#pragma unroll
  for (int c = 0; c < CPL; ++c) {
    const int col = lane + c * 64;
    float s = bias[col];
#pragma unroll
    for (int sp = 0; sp < 4; ++sp)
      s += part[((size_t)sp * NROW + row) * H + col];
    v[c] = s;
  }
  float sum = 0;
#pragma unroll
  for (int c = 0; c < CPL; ++c) sum += v[c];
#pragma unroll
  for (int o = 32; o > 0; o >>= 1) sum += __shfl_xor(sum, o);
  const float mu = sum / H;
  float vs = 0;
#pragma unroll
  for (int c = 0; c < CPL; ++c) { float d = v[c] - mu; vs += d * d; }
#pragma unroll
  for (int o = 32; o > 0; o >>= 1) vs += __shfl_xor(vs, o);
  const float rstd = rsqrtf(vs / H + 1e-5f);
#pragma unroll
  for (int c = 0; c < CPL; ++c) {
    const int col = lane + c * 64;
    float h = (v[c] - mu) * rstd * g[col] + be[col];
    if (ACT) h = (h > 0.f) ? h : 0.01f * h;
    sh[wid][col] = h;
  }
  __syncthreads();
  if (lane < H2) {
    float d = 0;
#pragma unroll 8
    for (int k = 0; k < H; ++k) d += sh[wid][k] * sW[k * H2 + lane];
    tT[(size_t)lane * NROW + row] = f2bf(d);
  }
}

// ------- final: sum splits + bias + LN + leaky + @Wl+bl + log_softmax -------
__global__ __launch_bounds__(256) void reduce_final(
    const float* __restrict__ part, const float* __restrict__ bias,
    const float* __restrict__ g, const float* __restrict__ be,
    const float* __restrict__ Wl, const float* __restrict__ bl,
    float* __restrict__ out) {
  __shared__ float sW[32 * 20];
  __shared__ float sbl[20];
  __shared__ float sh[4][32];
  __shared__ float sl[4][20];
  const int t = threadIdx.x;
  for (int i = t; i < 640; i += 256) sW[i] = Wl[i];
  if (t < 20) sbl[t] = bl[t];
  __syncthreads();
  const int wid = t >> 6, lane = t & 63;
  const int row = blockIdx.x * 4 + wid;
  const int col = lane & 31;  // lanes 32..63 duplicate cols 0..31
  float v = bias[col];
#pragma unroll
  for (int sp = 0; sp < 4; ++sp)
    v += part[((size_t)sp * NROW + row) * 32 + col];
  float sum = v;
#pragma unroll
  for (int o = 32; o > 0; o >>= 1) sum += __shfl_xor(sum, o);
  const float mu = sum / 64.f;  // values duplicated 2x across the wave
  float d0 = v - mu;
  float vs = d0 * d0;
#pragma unroll
  for (int o = 32; o > 0; o >>= 1) vs += __shfl_xor(vs, o);
  const float rstd = rsqrtf(vs / 64.f + 1e-5f);
  float h = (v - mu) * rstd * g[col] + be[col];
  h = (h > 0.f) ? h : 0.01f * h;
  if (lane < 32) sh[wid][col] = h;
  __syncthreads();
  if (lane < 20) {
    float lg = sbl[lane];
#pragma unroll
    for (int k = 0; k < 32; ++k) lg += sh[wid][k] * sW[k * 20 + lane];
    sl[wid][lane] = lg;
  }
  __syncthreads();
  if (lane < 20) {
    float mx = -1e30f;
#pragma unroll
    for (int k = 0; k < 20; ++k) mx = fmaxf(mx, sl[wid][k]);
    float se = 0.f;
#pragma unroll
    for (int k = 0; k < 20; ++k) se += expf(sl[wid][k] - mx);
    out[(size_t)row * 20 + lane] = sl[wid][lane] - mx - logf(se);
  }
}

extern "C" void kernel_launch(void* const* d_in, const int* in_sizes, int n_in,
                              void* d_out, int out_size, void* d_ws,
                              size_t ws_size, hipStream_t stream) {
  const float* x    = (const float*)d_in[0];
  const float* adj0 = (const float*)d_in[1];
  const float* adj1 = (const float*)d_in[2];
  const float* adj2 = (const float*)d_in[3];
  const float* W0   = (const float*)d_in[4];
  const float* b0   = (const float*)d_in[5];
  const float* W1   = (const float*)d_in[6];
  const float* b1   = (const float*)d_in[7];
  const float* W2   = (const float*)d_in[8];
  const float* b2   = (const float*)d_in[9];
  const float* g0   = (const float*)d_in[10];
  const float* be0  = (const float*)d_in[11];
  const float* g1   = (const float*)d_in[12];
  const float* be1  = (const float*)d_in[13];
  const float* g2   = (const float*)d_in[14];
  const float* be2  = (const float*)d_in[15];
  const float* Wl   = (const float*)d_in[16];
  const float* bl   = (const float*)d_in[17];
  float* out = (float*)d_out;

  char* ws = (char*)d_ws;
  float* part =          (float*)(ws);                      // 4*12288*128*4 = 25165824 B
  unsigned short* t0T = (unsigned short*)(ws + 25165824);   // 128*12288*2 = 3145728 B
  unsigned short* t1T = (unsigned short*)(ws + 25165824 + 3145728);          // 1572864 B
  unsigned short* t2T = (unsigned short*)(ws + 25165824 + 3145728 + 1572864); // 786432 B

  xw_kernel<<<NROW / 16, 256, 0, stream>>>(x, W0, t0T);
  gcn_gemm<128><<<(NROW / 64) * 4, 256, 0, stream>>>(adj0, t0T, part);
  reduce_ln<128, 64, false><<<NROW / 4, 256, 0, stream>>>(part, b0, g0, be0, W1, t1T);
  gcn_gemm<64><<<(NROW / 64) * 4, 256, 0, stream>>>(adj1, t1T, part);
  reduce_ln<64, 32, true><<<NROW / 4, 256, 0, stream>>>(part, b1, g1, be1, W2, t2T);
  gcn_gemm<32><<<(NROW / 64) * 4, 256, 0, stream>>>(adj2, t2T, part);
  reduce_final<<<NROW / 4, 256, 0, stream>>>(part, b2, g2, be2, Wl, bl, out);
}

// Round 5
// 465.520 us; speedup vs baseline: 1.2090x; 1.2090x over previous
//
#include <hip/hip_runtime.h>
#include <cstdint>
#include <cstddef>

typedef __attribute__((ext_vector_type(8))) short short8;
typedef __attribute__((ext_vector_type(4))) float f32x4;

#define DEV __device__ __forceinline__

DEV unsigned short f2bf(float f) {
  unsigned int u = __float_as_uint(f);
  u += 0x7fffu + ((u >> 16) & 1u);   // round-to-nearest-even
  return (unsigned short)(u >> 16);
}

DEV unsigned int pk2(float a, float b) {
  return (unsigned int)f2bf(a) | ((unsigned int)f2bf(b) << 16);
}

// async 16B global -> LDS (wave-uniform LDS base; HW adds lane*16)
DEV void glds16(const void* g, void* l) {
  __builtin_amdgcn_global_load_lds(
      (const __attribute__((address_space(1))) void*)g,
      (__attribute__((address_space(3))) void*)l, 16, 0, 0);
}

constexpr int NROW = 12288;

// ---------------- P0: t0T = (x @ W0)^T  -> bf16 [128][12288] ----------------
__global__ __launch_bounds__(256) void xw_kernel(
    const float* __restrict__ x, const float* __restrict__ W0,
    unsigned short* __restrict__ t0T) {
  __shared__ float sW[128 * 128];
  __shared__ float sx[16][128];
  const int t = threadIdx.x;
  for (int i = t; i < 128 * 128; i += 256) sW[i] = W0[i];
  const int r0 = blockIdx.x * 16;
  for (int i = t; i < 16 * 128; i += 256)
    sx[i >> 7][i & 127] = x[(size_t)(r0 + (i >> 7)) * 128 + (i & 127)];
  __syncthreads();
  const int c = t & 127;   // output column 0..127
  const int rg = t >> 7;   // row group: rows rg*8 .. rg*8+7
  float acc[8] = {0, 0, 0, 0, 0, 0, 0, 0};
  for (int k = 0; k < 128; ++k) {
    float w = sW[k * 128 + c];
#pragma unroll
    for (int j = 0; j < 8; ++j) acc[j] += sx[rg * 8 + j][k] * w;
  }
  uint4 o;
  o.x = pk2(acc[0], acc[1]);
  o.y = pk2(acc[2], acc[3]);
  o.z = pk2(acc[4], acc[5]);
  o.w = pk2(acc[6], acc[7]);
  *(uint4*)(t0T + (size_t)c * NROW + r0 + rg * 8) = o;
}

// ------------- big GEMM: part[split] = adj_chunk @ t   (bf16 MFMA) -----------
// A: [12288][12288] f32 (adj), BT: [H][12288] bf16 (t transposed)
// part: [KSPLIT][12288][H] f32
// Structure = R3 (B via global_load_lds double-buffer, raw s_barrier +
// counted vmcnt, XOR-swizzled A LDS, BK=64). ONE change vs R3: A is fetched
// in supersteps of 3 K-steps (768B-contiguous burst window per row group)
// into a 48-VGPR set, dribbled into the A double-buffer one 64-col slice
// per step. Set S+1 issued during step 3S+1 (vmcnt(12) keeps it in flight
// across that barrier); other barriers vmcnt(0) (nothing else outstanding).
template <int H>
__global__ __launch_bounds__(256, 3) void gcn_gemm(
    const float* __restrict__ A, const unsigned short* __restrict__ BT,
    float* __restrict__ part) {
  constexpr int KSPLIT = 4;
  constexpr int BM = 64, BK = 64;
  constexpr int WN = (H >= 64) ? 2 : 1;
  constexpr int WM = 4 / WN;
  constexpr int MR = BM / (WM * 16);
  constexpr int NR = H / (WN * 16);
  constexpr int NB = H / 32;                    // B DMA rounds (per thread)
  constexpr int KSTEPS = (NROW / KSPLIT) / BK;  // 48 = 3*16
  constexpr int NSUP = KSTEPS / 3;              // 16 supersteps
  constexpr int BBYTES = H * 128;               // one B^T tile (bf16)
  static_assert(KSTEPS % 3 == 0, "");

  __shared__ alignas(16) char lds[16384 + 2 * BBYTES];
  char* ldsB = lds + 16384;

  const int t = threadIdx.x;
  const int nmb = NROW / BM;  // 192
  const int bm = blockIdx.x % nmb;
  const int split = blockIdx.x / nmb;
  const int k0 = split * (NROW / KSPLIT);

  // ---- A staging: thread (r=t>>2, q=t&3); per superstep reads 3 slices of
  //      16 floats (64B) at cols S*192 + j*64 + q*16 — 4 threads/row cover
  //      768B of the row in one burst window ----
  const int r = t >> 2, q = t & 3;
  const float* aptr = A + (size_t)(bm * BM + r) * NROW + k0 + q * 16;
  const int sw = (r & 7) << 4;
  const int aw0 = (r * 128 + q * 32) ^ sw;         // swizzled byte offsets
  const int aw1 = (r * 128 + q * 32 + 16) ^ sw;

  // ---- B^T staging source: swizzle folded into global address ----
  const int nB0 = t >> 3;                    // row within round (+32/round)
  const int wB = (t & 7) ^ (nB0 & 7);        // pre-swizzled 16B chunk in row
  const unsigned short* bptr = BT + (size_t)nB0 * NROW + k0 + wB * 8;
  const int wid = t >> 6;
  char* ldsBw = ldsB + wid * 1024;           // wave-uniform B DMA base

  // ---- MFMA fragment LDS offsets (R3, unchanged) ----
  const int lane = t & 63;
  const int l15 = lane & 15;
  const int loct = lane >> 4;
  const int wm = wid / WN;
  const int wn = wid % WN;
  int aoff[MR][2], boff[NR][2];
#pragma unroll
  for (int m = 0; m < MR; ++m)
#pragma unroll
    for (int kk = 0; kk < 2; ++kk) {
      int row = wm * (MR * 16) + m * 16 + l15;
      aoff[m][kk] = (row * 128 + kk * 64 + loct * 16) ^ ((row & 7) << 4);
    }
#pragma unroll
  for (int n = 0; n < NR; ++n)
#pragma unroll
    for (int kk = 0; kk < 2; ++kk) {
      int nn = wn * (NR * 16) + n * 16 + l15;
      boff[n][kk] = (nn * 128 + kk * 64 + loct * 16) ^ ((nn & 7) << 4);
    }

  f32x4 acc[MR][NR];
#pragma unroll
  for (int m = 0; m < MR; ++m)
#pragma unroll
    for (int n = 0; n < NR; ++n) acc[m][n] = {0.f, 0.f, 0.f, 0.f};

  float4 av[12];   // one superstep's A (48 VGPR)

  auto issueSuper = [&](int S) {
#pragma unroll
    for (int j = 0; j < 3; ++j)
#pragma unroll
      for (int i = 0; i < 4; ++i)
        av[j * 4 + i] = *(const float4*)(aptr + S * 192 + j * 64 + i * 4);
  };
  auto glB = [&](int s, int buf) {
#pragma unroll
    for (int j = 0; j < NB; ++j)
      glds16(bptr + (size_t)j * 32 * NROW + s * BK,
             ldsBw + buf * BBYTES + j * 4096);
  };
  auto cvtWrite = [&](int j, int buf) {   // write slice j into A buf
    char* wb = lds + buf * 8192;
    uint4 w0, w1;
    w0.x = pk2(av[j * 4 + 0].x, av[j * 4 + 0].y);
    w0.y = pk2(av[j * 4 + 0].z, av[j * 4 + 0].w);
    w0.z = pk2(av[j * 4 + 1].x, av[j * 4 + 1].y);
    w0.w = pk2(av[j * 4 + 1].z, av[j * 4 + 1].w);
    w1.x = pk2(av[j * 4 + 2].x, av[j * 4 + 2].y);
    w1.y = pk2(av[j * 4 + 2].z, av[j * 4 + 2].w);
    w1.z = pk2(av[j * 4 + 3].x, av[j * 4 + 3].y);
    w1.w = pk2(av[j * 4 + 3].z, av[j * 4 + 3].w);
    *(uint4*)(wb + aw0) = w0;
    *(uint4*)(wb + aw1) = w1;
  };
  auto compute = [&](int buf) {
    const char* lA = lds + buf * 8192;
    const char* lB = ldsB + buf * BBYTES;
#pragma unroll
    for (int kk = 0; kk < 2; ++kk) {
      short8 af[MR], bfv[NR];
#pragma unroll
      for (int m = 0; m < MR; ++m) af[m] = *(const short8*)(lA + aoff[m][kk]);
#pragma unroll
      for (int n = 0; n < NR; ++n) bfv[n] = *(const short8*)(lB + boff[n][kk]);
#pragma unroll
      for (int m = 0; m < MR; ++m)
#pragma unroll
        for (int n = 0; n < NR; ++n)
          acc[m][n] = __builtin_amdgcn_mfma_f32_16x16x32_bf16(
              af[m], bfv[n], acc[m][n], 0, 0, 0);
    }
  };

  // ---- Prologue: set0 burst; B(0) DMA; A slice0 -> buf0 ----
  issueSuper(0);
  glB(0, 0);
  cvtWrite(0, 0);          // compiler waits av arrival
  asm volatile("s_waitcnt vmcnt(0) lgkmcnt(0)" ::: "memory");
  __builtin_amdgcn_s_barrier();
  __builtin_amdgcn_sched_barrier(0);

  for (int S = 0; S < NSUP; ++S) {
    const int b = S & 1;   // parity of step 3S
    // ---- step 3S: stage (3S+1) ----
    glB(3 * S + 1, b ^ 1);
    compute(b);
    cvtWrite(1, b ^ 1);
    asm volatile("s_waitcnt vmcnt(0) lgkmcnt(0)" ::: "memory");
    __builtin_amdgcn_s_barrier();
    __builtin_amdgcn_sched_barrier(0);
    // ---- step 3S+1: stage (3S+2); burst-issue set S+1 ----
    glB(3 * S + 2, b);
    compute(b ^ 1);
    cvtWrite(2, b);
    if (S + 1 < NSUP) {
      issueSuper(S + 1);   // 12 loads stay in flight across barrier
      asm volatile("s_waitcnt vmcnt(12) lgkmcnt(0)" ::: "memory");
    } else {
      asm volatile("s_waitcnt vmcnt(0) lgkmcnt(0)" ::: "memory");
    }
    __builtin_amdgcn_s_barrier();
    __builtin_amdgcn_sched_barrier(0);
    // ---- step 3S+2: stage (3S+3) from NEW set ----
    if (S + 1 < NSUP) {
      glB(3 * S + 3, b ^ 1);
      compute(b);
      cvtWrite(0, b ^ 1);  // compiler waits new set arrival
      asm volatile("s_waitcnt vmcnt(0) lgkmcnt(0)" ::: "memory");
      __builtin_amdgcn_s_barrier();
      __builtin_amdgcn_sched_barrier(0);
    } else {
      compute(b);          // final step, no staging
    }
  }

  float* pout = part + ((size_t)split * NROW + (size_t)bm * BM) * H;
#pragma unroll
  for (int m = 0; m < MR; ++m) {
    const int row = wm * (MR * 16) + m * 16 + loct * 4;
#pragma unroll
    for (int n = 0; n < NR; ++n) {
      const int col = wn * (NR * 16) + n * 16 + l15;
#pragma unroll
      for (int rr = 0; rr < 4; ++rr)
        pout[(size_t)(row + rr) * H + col] = acc[m][n][rr];
    }
  }
}

// ------- reduce: sum splits + bias + LN + (leaky) + @Wnext -> t_next^T -------
template <int H, int H2, bool ACT>
__global__ __launch_bounds__(256) void reduce_ln(
    const float* __restrict__ part, const float* __restrict__ bias,
    const float* __restrict__ g, const float* __restrict__ be,
    const float* __restrict__ Wn, unsigned short* __restrict__ tT) {
  __shared__ float sW[H * H2];
  __shared__ float sh[4][H];
  const int t = threadIdx.x;
  for (int i = t; i < H * H2; i += 256) sW[i] = Wn[i];
  __syncthreads();

  const int wid = t >> 6, lane = t & 63;
  const int row = blockIdx.x * 4 + wid;
  constexpr int CPL = H / 64;
  float v[CPL];
#pragma unroll
  for (int c = 0; c < CPL; ++c) {
    const int col = lane + c * 64;
    float s = bias[col];
#pragma unroll
    for (int sp = 0; sp < 4; ++sp)
      s += part[((size_t)sp * NROW + row) * H + col];
    v[c] = s;
  }
  float sum = 0;
#pragma unroll
  for (int c = 0; c < CPL; ++c) sum += v[c];
#pragma unroll
  for (int o = 32; o > 0; o >>= 1) sum += __shfl_xor(sum, o);
  const float mu = sum / H;
  float vs = 0;
#pragma unroll
  for (int c = 0; c < CPL; ++c) { float d = v[c] - mu; vs += d * d; }
#pragma unroll
  for (int o = 32; o > 0; o >>= 1) vs += __shfl_xor(vs, o);
  const float rstd = rsqrtf(vs / H + 1e-5f);
#pragma unroll
  for (int c = 0; c < CPL; ++c) {
    const int col = lane + c * 64;
    float h = (v[c] - mu) * rstd * g[col] + be[col];
    if (ACT) h = (h > 0.f) ? h : 0.01f * h;
    sh[wid][col] = h;
  }
  __syncthreads();
  if (lane < H2) {
    float d = 0;
#pragma unroll 8
    for (int k = 0; k < H; ++k) d += sh[wid][k] * sW[k * H2 + lane];
    tT[(size_t)lane * NROW + row] = f2bf(d);
  }
}

// ------- final: sum splits + bias + LN + leaky + @Wl+bl + log_softmax -------
__global__ __launch_bounds__(256) void reduce_final(
    const float* __restrict__ part, const float* __restrict__ bias,
    const float* __restrict__ g, const float* __restrict__ be,
    const float* __restrict__ Wl, const float* __restrict__ bl,
    float* __restrict__ out) {
  __shared__ float sW[32 * 20];
  __shared__ float sbl[20];
  __shared__ float sh[4][32];
  __shared__ float sl[4][20];
  const int t = threadIdx.x;
  for (int i = t; i < 640; i += 256) sW[i] = Wl[i];
  if (t < 20) sbl[t] = bl[t];
  __syncthreads();
  const int wid = t >> 6, lane = t & 63;
  const int row = blockIdx.x * 4 + wid;
  const int col = lane & 31;  // lanes 32..63 duplicate cols 0..31
  float v = bias[col];
#pragma unroll
  for (int sp = 0; sp < 4; ++sp)
    v += part[((size_t)sp * NROW + row) * 32 + col];
  float sum = v;
#pragma unroll
  for (int o = 32; o > 0; o >>= 1) sum += __shfl_xor(sum, o);
  const float mu = sum / 64.f;  // values duplicated 2x across the wave
  float d0 = v - mu;
  float vs = d0 * d0;
#pragma unroll
  for (int o = 32; o > 0; o >>= 1) vs += __shfl_xor(vs, o);
  const float rstd = rsqrtf(vs / 64.f + 1e-5f);
  float h = (v - mu) * rstd * g[col] + be[col];
  h = (h > 0.f) ? h : 0.01f * h;
  if (lane < 32) sh[wid][col] = h;
  __syncthreads();
  if (lane < 20) {
    float lg = sbl[lane];
#pragma unroll
    for (int k = 0; k < 32; ++k) lg += sh[wid][k] * sW[k * 20 + lane];
    sl[wid][lane] = lg;
  }
  __syncthreads();
  if (lane < 20) {
    float mx = -1e30f;
#pragma unroll
    for (int k = 0; k < 20; ++k) mx = fmaxf(mx, sl[wid][k]);
    float se = 0.f;
#pragma unroll
    for (int k = 0; k < 20; ++k) se += expf(sl[wid][k] - mx);
    out[(size_t)row * 20 + lane] = sl[wid][lane] - mx - logf(se);
  }
}

extern "C" void kernel_launch(void* const* d_in, const int* in_sizes, int n_in,
                              void* d_out, int out_size, void* d_ws,
                              size_t ws_size, hipStream_t stream) {
  const float* x    = (const float*)d_in[0];
  const float* adj0 = (const float*)d_in[1];
  const float* adj1 = (const float*)d_in[2];
  const float* adj2 = (const float*)d_in[3];
  const float* W0   = (const float*)d_in[4];
  const float* b0   = (const float*)d_in[5];
  const float* W1   = (const float*)d_in[6];
  const float* b1   = (const float*)d_in[7];
  const float* W2   = (const float*)d_in[8];
  const float* b2   = (const float*)d_in[9];
  const float* g0   = (const float*)d_in[10];
  const float* be0  = (const float*)d_in[11];
  const float* g1   = (const float*)d_in[12];
  const float* be1  = (const float*)d_in[13];
  const float* g2   = (const float*)d_in[14];
  const float* be2  = (const float*)d_in[15];
  const float* Wl   = (const float*)d_in[16];
  const float* bl   = (const float*)d_in[17];
  float* out = (float*)d_out;

  char* ws = (char*)d_ws;
  float* part =          (float*)(ws);                      // 4*12288*128*4 = 25165824 B
  unsigned short* t0T = (unsigned short*)(ws + 25165824);   // 128*12288*2 = 3145728 B
  unsigned short* t1T = (unsigned short*)(ws + 25165824 + 3145728);          // 1572864 B
  unsigned short* t2T = (unsigned short*)(ws + 25165824 + 3145728 + 1572864); // 786432 B

  xw_kernel<<<NROW / 16, 256, 0, stream>>>(x, W0, t0T);
  gcn_gemm<128><<<(NROW / 64) * 4, 256, 0, stream>>>(adj0, t0T, part);
  reduce_ln<128, 64, false><<<NROW / 4, 256, 0, stream>>>(part, b0, g0, be0, W1, t1T);
  gcn_gemm<64><<<(NROW / 64) * 4, 256, 0, stream>>>(adj1, t1T, part);
  reduce_ln<64, 32, true><<<NROW / 4, 256, 0, stream>>>(part, b1, g1, be1, W2, t2T);
  gcn_gemm<32><<<(NROW / 64) * 4, 256, 0, stream>>>(adj2, t2T, part);
  reduce_final<<<NROW / 4, 256, 0, stream>>>(part, b2, g2, be2, Wl, bl, out);
}

// Round 6
// 457.404 us; speedup vs baseline: 1.2304x; 1.0177x over previous
//
#include <hip/hip_runtime.h>
#include <cstdint>
#include <cstddef>

typedef __attribute__((ext_vector_type(8))) short short8;
typedef __attribute__((ext_vector_type(4))) float f32x4;

#define DEV __device__ __forceinline__

DEV unsigned short f2bf(float f) {
  unsigned int u = __float_as_uint(f);
  u += 0x7fffu + ((u >> 16) & 1u);   // round-to-nearest-even
  return (unsigned short)(u >> 16);
}

DEV unsigned int pk2(float a, float b) {
  return (unsigned int)f2bf(a) | ((unsigned int)f2bf(b) << 16);
}

// async 16B global -> LDS (wave-uniform LDS base; HW adds lane*16)
DEV void glds16(const void* g, void* l) {
  __builtin_amdgcn_global_load_lds(
      (const __attribute__((address_space(1))) void*)g,
      (__attribute__((address_space(3))) void*)l, 16, 0, 0);
}

constexpr int NROW = 12288;

// ---------------- P0: t0T = (x @ W0)^T  -> bf16 [128][12288] ----------------
__global__ __launch_bounds__(256) void xw_kernel(
    const float* __restrict__ x, const float* __restrict__ W0,
    unsigned short* __restrict__ t0T) {
  __shared__ float sW[128 * 128];
  __shared__ float sx[16][128];
  const int t = threadIdx.x;
  for (int i = t; i < 128 * 128; i += 256) sW[i] = W0[i];
  const int r0 = blockIdx.x * 16;
  for (int i = t; i < 16 * 128; i += 256)
    sx[i >> 7][i & 127] = x[(size_t)(r0 + (i >> 7)) * 128 + (i & 127)];
  __syncthreads();
  const int c = t & 127;   // output column 0..127
  const int rg = t >> 7;   // row group: rows rg*8 .. rg*8+7
  float acc[8] = {0, 0, 0, 0, 0, 0, 0, 0};
  for (int k = 0; k < 128; ++k) {
    float w = sW[k * 128 + c];
#pragma unroll
    for (int j = 0; j < 8; ++j) acc[j] += sx[rg * 8 + j][k] * w;
  }
  uint4 o;
  o.x = pk2(acc[0], acc[1]);
  o.y = pk2(acc[2], acc[3]);
  o.z = pk2(acc[4], acc[5]);
  o.w = pk2(acc[6], acc[7]);
  *(uint4*)(t0T + (size_t)c * NROW + r0 + rg * 8) = o;
}

// ------------- big GEMM: part[split] = adj_chunk @ t   (bf16 MFMA) -----------
// A: [12288][12288] f32 (adj), BT: [H][12288] bf16 (t transposed)
// part: [KSPLIT][12288][H] f32
// Structure = R5 (superstep A bursts, B global_load_lds double-buffer, raw
// s_barrier + counted vmcnt, XOR-swizzled LDS). ONE change vs R5:
// split-per-XCD block remap — XCD = blockIdx%8 (HW round-robin); we derive
// split = xcd>>1 so each XCD serves exactly ONE K-split. B working set per
// XCD-L2 drops 4x (3MB -> 768KB on layer0) and the 96 co-resident same-split
// blocks share one B stream -> B stays L2-hit despite the A stream flushing
// the L2. bm contiguous within an XCD.
template <int H>
__global__ __launch_bounds__(256, 3) void gcn_gemm(
    const float* __restrict__ A, const unsigned short* __restrict__ BT,
    float* __restrict__ part) {
  constexpr int KSPLIT = 4;
  constexpr int BM = 64, BK = 64;
  constexpr int WN = (H >= 64) ? 2 : 1;
  constexpr int WM = 4 / WN;
  constexpr int MR = BM / (WM * 16);
  constexpr int NR = H / (WN * 16);
  constexpr int NB = H / 32;                    // B DMA rounds (per thread)
  constexpr int KSTEPS = (NROW / KSPLIT) / BK;  // 48 = 3*16
  constexpr int NSUP = KSTEPS / 3;              // 16 supersteps
  constexpr int BBYTES = H * 128;               // one B^T tile (bf16)
  static_assert(KSTEPS % 3 == 0, "");

  __shared__ alignas(16) char lds[16384 + 2 * BBYTES];
  char* ldsB = lds + 16384;

  const int t = threadIdx.x;
  // ---- split-per-XCD remap (grid = 768 = 8 XCD * 96) ----
  const int xcd = blockIdx.x & 7;
  const int idx = blockIdx.x >> 3;          // 0..95
  const int split = xcd >> 1;               // one split per XCD
  const int bm = ((xcd & 1) ? 96 : 0) + idx;
  const int k0 = split * (NROW / KSPLIT);

  // ---- A staging: thread (r=t>>2, q=t&3); per superstep reads 3 slices of
  //      16 floats (64B) at cols S*192 + j*64 + q*16 — 4 threads/row cover
  //      768B of the row in one burst window ----
  const int r = t >> 2, q = t & 3;
  const float* aptr = A + (size_t)(bm * BM + r) * NROW + k0 + q * 16;
  const int sw = (r & 7) << 4;
  const int aw0 = (r * 128 + q * 32) ^ sw;         // swizzled byte offsets
  const int aw1 = (r * 128 + q * 32 + 16) ^ sw;

  // ---- B^T staging source: swizzle folded into global address ----
  const int nB0 = t >> 3;                    // row within round (+32/round)
  const int wB = (t & 7) ^ (nB0 & 7);        // pre-swizzled 16B chunk in row
  const unsigned short* bptr = BT + (size_t)nB0 * NROW + k0 + wB * 8;
  const int wid = t >> 6;
  char* ldsBw = ldsB + wid * 1024;           // wave-uniform B DMA base

  // ---- MFMA fragment LDS offsets ----
  const int lane = t & 63;
  const int l15 = lane & 15;
  const int loct = lane >> 4;
  const int wm = wid / WN;
  const int wn = wid % WN;
  int aoff[MR][2], boff[NR][2];
#pragma unroll
  for (int m = 0; m < MR; ++m)
#pragma unroll
    for (int kk = 0; kk < 2; ++kk) {
      int row = wm * (MR * 16) + m * 16 + l15;
      aoff[m][kk] = (row * 128 + kk * 64 + loct * 16) ^ ((row & 7) << 4);
    }
#pragma unroll
  for (int n = 0; n < NR; ++n)
#pragma unroll
    for (int kk = 0; kk < 2; ++kk) {
      int nn = wn * (NR * 16) + n * 16 + l15;
      boff[n][kk] = (nn * 128 + kk * 64 + loct * 16) ^ ((nn & 7) << 4);
    }

  f32x4 acc[MR][NR];
#pragma unroll
  for (int m = 0; m < MR; ++m)
#pragma unroll
    for (int n = 0; n < NR; ++n) acc[m][n] = {0.f, 0.f, 0.f, 0.f};

  float4 av[12];   // one superstep's A (48 VGPR)

  auto issueSuper = [&](int S) {
#pragma unroll
    for (int j = 0; j < 3; ++j)
#pragma unroll
      for (int i = 0; i < 4; ++i)
        av[j * 4 + i] = *(const float4*)(aptr + S * 192 + j * 64 + i * 4);
  };
  auto glB = [&](int s, int buf) {
#pragma unroll
    for (int j = 0; j < NB; ++j)
      glds16(bptr + (size_t)j * 32 * NROW + s * BK,
             ldsBw + buf * BBYTES + j * 4096);
  };
  auto cvtWrite = [&](int j, int buf) {   // write slice j into A buf
    char* wb = lds + buf * 8192;
    uint4 w0, w1;
    w0.x = pk2(av[j * 4 + 0].x, av[j * 4 + 0].y);
    w0.y = pk2(av[j * 4 + 0].z, av[j * 4 + 0].w);
    w0.z = pk2(av[j * 4 + 1].x, av[j * 4 + 1].y);
    w0.w = pk2(av[j * 4 + 1].z, av[j * 4 + 1].w);
    w1.x = pk2(av[j * 4 + 2].x, av[j * 4 + 2].y);
    w1.y = pk2(av[j * 4 + 2].z, av[j * 4 + 2].w);
    w1.z = pk2(av[j * 4 + 3].x, av[j * 4 + 3].y);
    w1.w = pk2(av[j * 4 + 3].z, av[j * 4 + 3].w);
    *(uint4*)(wb + aw0) = w0;
    *(uint4*)(wb + aw1) = w1;
  };
  auto compute = [&](int buf) {
    const char* lA = lds + buf * 8192;
    const char* lB = ldsB + buf * BBYTES;
#pragma unroll
    for (int kk = 0; kk < 2; ++kk) {
      short8 af[MR], bfv[NR];
#pragma unroll
      for (int m = 0; m < MR; ++m) af[m] = *(const short8*)(lA + aoff[m][kk]);
#pragma unroll
      for (int n = 0; n < NR; ++n) bfv[n] = *(const short8*)(lB + boff[n][kk]);
#pragma unroll
      for (int m = 0; m < MR; ++m)
#pragma unroll
        for (int n = 0; n < NR; ++n)
          acc[m][n] = __builtin_amdgcn_mfma_f32_16x16x32_bf16(
              af[m], bfv[n], acc[m][n], 0, 0, 0);
    }
  };

  // ---- Prologue: set0 burst; B(0) DMA; A slice0 -> buf0 ----
  issueSuper(0);
  glB(0, 0);
  cvtWrite(0, 0);          // compiler waits av arrival
  asm volatile("s_waitcnt vmcnt(0) lgkmcnt(0)" ::: "memory");
  __builtin_amdgcn_s_barrier();
  __builtin_amdgcn_sched_barrier(0);

  for (int S = 0; S < NSUP; ++S) {
    const int b = S & 1;   // parity of step 3S
    // ---- step 3S: stage (3S+1) ----
    glB(3 * S + 1, b ^ 1);
    compute(b);
    cvtWrite(1, b ^ 1);
    asm volatile("s_waitcnt vmcnt(0) lgkmcnt(0)" ::: "memory");
    __builtin_amdgcn_s_barrier();
    __builtin_amdgcn_sched_barrier(0);
    // ---- step 3S+1: stage (3S+2); burst-issue set S+1 ----
    glB(3 * S + 2, b);
    compute(b ^ 1);
    cvtWrite(2, b);
    if (S + 1 < NSUP) {
      issueSuper(S + 1);   // 12 loads stay in flight across barrier
      asm volatile("s_waitcnt vmcnt(12) lgkmcnt(0)" ::: "memory");
    } else {
      asm volatile("s_waitcnt vmcnt(0) lgkmcnt(0)" ::: "memory");
    }
    __builtin_amdgcn_s_barrier();
    __builtin_amdgcn_sched_barrier(0);
    // ---- step 3S+2: stage (3S+3) from NEW set ----
    if (S + 1 < NSUP) {
      glB(3 * S + 3, b ^ 1);
      compute(b);
      cvtWrite(0, b ^ 1);  // compiler waits new set arrival
      asm volatile("s_waitcnt vmcnt(0) lgkmcnt(0)" ::: "memory");
      __builtin_amdgcn_s_barrier();
      __builtin_amdgcn_sched_barrier(0);
    } else {
      compute(b);          // final step, no staging
    }
  }

  float* pout = part + ((size_t)split * NROW + (size_t)bm * BM) * H;
#pragma unroll
  for (int m = 0; m < MR; ++m) {
    const int row = wm * (MR * 16) + m * 16 + loct * 4;
#pragma unroll
    for (int n = 0; n < NR; ++n) {
      const int col = wn * (NR * 16) + n * 16 + l15;
#pragma unroll
      for (int rr = 0; rr < 4; ++rr)
        pout[(size_t)(row + rr) * H + col] = acc[m][n][rr];
    }
  }
}

// ------- reduce: sum splits + bias + LN + (leaky) + @Wnext -> t_next^T -------
template <int H, int H2, bool ACT>
__global__ __launch_bounds__(256) void reduce_ln(
    const float* __restrict__ part, const float* __restrict__ bias,
    const float* __restrict__ g, const float* __restrict__ be,
    const float* __restrict__ Wn, unsigned short* __restrict__ tT) {
  __shared__ float sW[H * H2];
  __shared__ float sh[4][H];
  const int t = threadIdx.x;
  for (int i = t; i < H * H2; i += 256) sW[i] = Wn[i];
  __syncthreads();

  const int wid = t >> 6, lane = t & 63;
  const int row = blockIdx.x * 4 + wid;
  constexpr int CPL = H / 64;
  float v[CPL];
#pragma unroll
  for (int c = 0; c < CPL; ++c) {
    const int col = lane + c * 64;
    float s = bias[col];
#pragma unroll
    for (int sp = 0; sp < 4; ++sp)
      s += part[((size_t)sp * NROW + row) * H + col];
    v[c] = s;
  }
  float sum = 0;
#pragma unroll
  for (int c = 0; c < CPL; ++c) sum += v[c];
#pragma unroll
  for (int o = 32; o > 0; o >>= 1) sum += __shfl_xor(sum, o);
  const float mu = sum / H;
  float vs = 0;
#pragma unroll
  for (int c = 0; c < CPL; ++c) { float d = v[c] - mu; vs += d * d; }
#pragma unroll
  for (int o = 32; o > 0; o >>= 1) vs += __shfl_xor(vs, o);
  const float rstd = rsqrtf(vs / H + 1e-5f);
#pragma unroll
  for (int c = 0; c < CPL; ++c) {
    const int col = lane + c * 64;
    float h = (v[c] - mu) * rstd * g[col] + be[col];
    if (ACT) h = (h > 0.f) ? h : 0.01f * h;
    sh[wid][col] = h;
  }
  __syncthreads();
  if (lane < H2) {
    float d = 0;
#pragma unroll 8
    for (int k = 0; k < H; ++k) d += sh[wid][k] * sW[k * H2 + lane];
    tT[(size_t)lane * NROW + row] = f2bf(d);
  }
}

// ------- final: sum splits + bias + LN + leaky + @Wl+bl + log_softmax -------
__global__ __launch_bounds__(256) void reduce_final(
    const float* __restrict__ part, const float* __restrict__ bias,
    const float* __restrict__ g, const float* __restrict__ be,
    const float* __restrict__ Wl, const float* __restrict__ bl,
    float* __restrict__ out) {
  __shared__ float sW[32 * 20];
  __shared__ float sbl[20];
  __shared__ float sh[4][32];
  __shared__ float sl[4][20];
  const int t = threadIdx.x;
  for (int i = t; i < 640; i += 256) sW[i] = Wl[i];
  if (t < 20) sbl[t] = bl[t];
  __syncthreads();
  const int wid = t >> 6, lane = t & 63;
  const int row = blockIdx.x * 4 + wid;
  const int col = lane & 31;  // lanes 32..63 duplicate cols 0..31
  float v = bias[col];
#pragma unroll
  for (int sp = 0; sp < 4; ++sp)
    v += part[((size_t)sp * NROW + row) * 32 + col];
  float sum = v;
#pragma unroll
  for (int o = 32; o > 0; o >>= 1) sum += __shfl_xor(sum, o);
  const float mu = sum / 64.f;  // values duplicated 2x across the wave
  float d0 = v - mu;
  float vs = d0 * d0;
#pragma unroll
  for (int o = 32; o > 0; o >>= 1) vs += __shfl_xor(vs, o);
  const float rstd = rsqrtf(vs / 64.f + 1e-5f);
  float h = (v - mu) * rstd * g[col] + be[col];
  h = (h > 0.f) ? h : 0.01f * h;
  if (lane < 32) sh[wid][col] = h;
  __syncthreads();
  if (lane < 20) {
    float lg = sbl[lane];
#pragma unroll
    for (int k = 0; k < 32; ++k) lg += sh[wid][k] * sW[k * 20 + lane];
    sl[wid][lane] = lg;
  }
  __syncthreads();
  if (lane < 20) {
    float mx = -1e30f;
#pragma unroll
    for (int k = 0; k < 20; ++k) mx = fmaxf(mx, sl[wid][k]);
    float se = 0.f;
#pragma unroll
    for (int k = 0; k < 20; ++k) se += expf(sl[wid][k] - mx);
    out[(size_t)row * 20 + lane] = sl[wid][lane] - mx - logf(se);
  }
}

extern "C" void kernel_launch(void* const* d_in, const int* in_sizes, int n_in,
                              void* d_out, int out_size, void* d_ws,
                              size_t ws_size, hipStream_t stream) {
  const float* x    = (const float*)d_in[0];
  const float* adj0 = (const float*)d_in[1];
  const float* adj1 = (const float*)d_in[2];
  const float* adj2 = (const float*)d_in[3];
  const float* W0   = (const float*)d_in[4];
  const float* b0   = (const float*)d_in[5];
  const float* W1   = (const float*)d_in[6];
  const float* b1   = (const float*)d_in[7];
  const float* W2   = (const float*)d_in[8];
  const float* b2   = (const float*)d_in[9];
  const float* g0   = (const float*)d_in[10];
  const float* be0  = (const float*)d_in[11];
  const float* g1   = (const float*)d_in[12];
  const float* be1  = (const float*)d_in[13];
  const float* g2   = (const float*)d_in[14];
  const float* be2  = (const float*)d_in[15];
  const float* Wl   = (const float*)d_in[16];
  const float* bl   = (const float*)d_in[17];
  float* out = (float*)d_out;

  char* ws = (char*)d_ws;
  float* part =          (float*)(ws);                      // 4*12288*128*4 = 25165824 B
  unsigned short* t0T = (unsigned short*)(ws + 25165824);   // 128*12288*2 = 3145728 B
  unsigned short* t1T = (unsigned short*)(ws + 25165824 + 3145728);          // 1572864 B
  unsigned short* t2T = (unsigned short*)(ws + 25165824 + 3145728 + 1572864); // 786432 B

  xw_kernel<<<NROW / 16, 256, 0, stream>>>(x, W0, t0T);
  gcn_gemm<128><<<(NROW / 64) * 4, 256, 0, stream>>>(adj0, t0T, part);
  reduce_ln<128, 64, false><<<NROW / 4, 256, 0, stream>>>(part, b0, g0, be0, W1, t1T);
  gcn_gemm<64><<<(NROW / 64) * 4, 256, 0, stream>>>(adj1, t1T, part);
  reduce_ln<64, 32, true><<<NROW / 4, 256, 0, stream>>>(part, b1, g1, be1, W2, t2T);
  gcn_gemm<32><<<(NROW / 64) * 4, 256, 0, stream>>>(adj2, t2T, part);
  reduce_final<<<NROW / 4, 256, 0, stream>>>(part, b2, g2, be2, Wl, bl, out);
}